// Round 1
// baseline (267.859 us; speedup 1.0000x reference)
//
#include <hip/hip_runtime.h>
#include <hip/hip_bf16.h>
#include <math.h>

// Power-series of 64x64 matrices: out = (M + sum_{i=1..6} P_i)/sqrt(7),
// P_i = P_{i-1} * M / decay_i, P_0 = M.
// One 256-thread block (4 waves) per matrix. Wave w owns rows [16w,16w+16):
// its MFMA A-fragments and C-tile writes touch only that strip, so the main
// loop needs NO __syncthreads. B operand (= M, constant over stages) lives
// entirely in registers (16 frags hi + 16 lo = 64 VGPRs), loaded once from a
// transposed LDS copy. Split-precision: x = hi(bf16) + lo(bf16), product via
// 3 MFMA passes (hi*hi + hi*lo + lo*hi) -> ~2^-17 relative accuracy.

#define RDIM 64
#define LDSP 72   // padded bf16 row stride: 144 B, keeps 16 B alignment, spreads banks

using bf16x8 = __attribute__((ext_vector_type(8))) short;  // 8 bf16 = 4 VGPRs
using f32x4  = __attribute__((ext_vector_type(4))) float;

__device__ __forceinline__ short f2bf(float x) {
    __hip_bfloat16 h = __float2bfloat16(x);
    union { __hip_bfloat16 b; short s; } u; u.b = h; return u.s;
}
__device__ __forceinline__ float bf2f(short s) {
    union { short s; __hip_bfloat16 b; } u; u.s = s;
    return __bfloat162float(u.b);
}

__global__ __launch_bounds__(256) void power_series_kernel(
        const float* __restrict__ M, float* __restrict__ out) {
    __shared__ short PAhi[RDIM][LDSP];   // current P, row-major, hi part
    __shared__ short PAlo[RDIM][LDSP];   // current P, row-major, lo part
    __shared__ short MThi[RDIM][LDSP];   // M transposed (for B frags), hi
    __shared__ short MTlo[RDIM][LDSP];   // M transposed, lo

    const int tid  = threadIdx.x;
    const int lane = tid & 63;
    const int wave = tid >> 6;     // 0..3, owns rows [16w, 16w+16)
    const int l15  = lane & 15;
    const int quad = lane >> 4;    // 0..3

    const float* Mg = M   + (size_t)blockIdx.x * (RDIM * RDIM);
    float*       Og = out + (size_t)blockIdx.x * (RDIM * RDIM);

    // ---- stage M into LDS: row-major (P0) + transposed (B source), hi/lo split
    {
        const float4* Mg4 = reinterpret_cast<const float4*>(Mg);
        #pragma unroll
        for (int v = 0; v < 4; ++v) {
            float4 x = Mg4[tid + 256 * v];        // fully coalesced
            int e0  = (tid + 256 * v) * 4;        // flat element index
            int row = e0 >> 6;
            int col = e0 & 63;                    // multiple of 4 -> 8B aligned
            float xs[4] = {x.x, x.y, x.z, x.w};
            short hs[4], ls[4];
            #pragma unroll
            for (int j = 0; j < 4; ++j) {
                short h = f2bf(xs[j]);
                hs[j] = h;
                ls[j] = f2bf(xs[j] - bf2f(h));
            }
            short4 hv; hv.x = hs[0]; hv.y = hs[1]; hv.z = hs[2]; hv.w = hs[3];
            short4 lv; lv.x = ls[0]; lv.y = ls[1]; lv.z = ls[2]; lv.w = ls[3];
            *reinterpret_cast<short4*>(&PAhi[row][col]) = hv;
            *reinterpret_cast<short4*>(&PAlo[row][col]) = lv;
            #pragma unroll
            for (int j = 0; j < 4; ++j) {         // transposed scatter (once)
                MThi[col + j][row] = hs[j];
                MTlo[col + j][row] = ls[j];
            }
        }
    }
    __syncthreads();   // the ONLY barrier

    // ---- B fragments (constant over all 6 stages): B[k][n] = M[k][n]
    // lane holds B[kb*32 + quad*8 + j][16t + l15]  ==  MT[16t+l15][kb*32+quad*8 + j]
    bf16x8 bhi[4][2], blo[4][2];
    #pragma unroll
    for (int t = 0; t < 4; ++t) {
        #pragma unroll
        for (int kb = 0; kb < 2; ++kb) {
            int n = t * 16 + l15;
            int k = kb * 32 + quad * 8;
            bhi[t][kb] = *reinterpret_cast<const bf16x8*>(&MThi[n][k]);
            blo[t][kb] = *reinterpret_cast<const bf16x8*>(&MTlo[n][k]);
        }
    }

    // ---- decay constants (exact integer variances, double sqrt once per thread)
    const double V[7] = {1.0, 64.0, 4104.0, 263696.0, 17021060.0,
                         1104218816.0, 72260728960.0};
    float invd[7];
    invd[0] = 1.0f;
    #pragma unroll
    for (int i = 1; i < 7; ++i) invd[i] = (float)(1.0 / sqrt(V[i] / V[i - 1]));

    f32x4 acc[4];
    #pragma unroll
    for (int t = 0; t < 4; ++t) acc[t] = (f32x4){0.f, 0.f, 0.f, 0.f};

    const int arow = wave * 16 + l15;   // A-fragment row for this lane

    #pragma unroll
    for (int s = 1; s < 7; ++s) {
        // A fragments of current P (this wave's own strip only)
        bf16x8 ahi0 = *reinterpret_cast<const bf16x8*>(&PAhi[arow][ 0 + quad * 8]);
        bf16x8 ahi1 = *reinterpret_cast<const bf16x8*>(&PAhi[arow][32 + quad * 8]);
        bf16x8 alo0 = *reinterpret_cast<const bf16x8*>(&PAlo[arow][ 0 + quad * 8]);
        bf16x8 alo1 = *reinterpret_cast<const bf16x8*>(&PAlo[arow][32 + quad * 8]);
        float inv = invd[s];
        #pragma unroll
        for (int t = 0; t < 4; ++t) {
            f32x4 c = (f32x4){0.f, 0.f, 0.f, 0.f};
            c = __builtin_amdgcn_mfma_f32_16x16x32_bf16(ahi0, bhi[t][0], c, 0, 0, 0);
            c = __builtin_amdgcn_mfma_f32_16x16x32_bf16(ahi1, bhi[t][1], c, 0, 0, 0);
            c = __builtin_amdgcn_mfma_f32_16x16x32_bf16(ahi0, blo[t][0], c, 0, 0, 0);
            c = __builtin_amdgcn_mfma_f32_16x16x32_bf16(ahi1, blo[t][1], c, 0, 0, 0);
            c = __builtin_amdgcn_mfma_f32_16x16x32_bf16(alo0, bhi[t][0], c, 0, 0, 0);
            c = __builtin_amdgcn_mfma_f32_16x16x32_bf16(alo1, bhi[t][1], c, 0, 0, 0);
            #pragma unroll
            for (int r = 0; r < 4; ++r) {
                float p = c[r] * inv;       // P_s element
                acc[t][r] += p;
                if (s < 6) {                // last stage's P is never read again
                    int row = wave * 16 + quad * 4 + r;   // C/D layout
                    int col = t * 16 + l15;
                    short h = f2bf(p);
                    PAhi[row][col] = h;
                    PAlo[row][col] = f2bf(p - bf2f(h));
                }
            }
        }
        // Intra-wave DS ordering guarantees stage s+1 reads see these writes;
        // no other wave touches this 16-row strip.
    }

    // ---- epilogue: out = (M + acc) / sqrt(7)
    const float oscale = (float)(1.0 / sqrt(7.0));
    #pragma unroll
    for (int t = 0; t < 4; ++t) {
        #pragma unroll
        for (int r = 0; r < 4; ++r) {
            int row = wave * 16 + quad * 4 + r;
            int col = t * 16 + l15;
            float m = Mg[row * 64 + col];        // hot in L2 from staging read
            Og[row * 64 + col] = (acc[t][r] + m) * oscale;
        }
    }
}

extern "C" void kernel_launch(void* const* d_in, const int* in_sizes, int n_in,
                              void* d_out, int out_size, void* d_ws, size_t ws_size,
                              hipStream_t stream) {
    const float* M = (const float*)d_in[0];
    float* out = (float*)d_out;
    const int nmat = in_sizes[0] / (RDIM * RDIM);   // 8192
    power_series_kernel<<<dim3(nmat), dim3(256), 0, stream>>>(M, out);
}